// Round 5
// baseline (9326.689 us; speedup 1.0000x reference)
//
#include <hip/hip_runtime.h>
#include <cstdint>
#include <cstddef>

// ---------------- problem dims ----------------
#define TSTEPS 256
#define BATCH  64
#define OBSD   512
#define HIDD   1024
#define NACT   128
#define TOK    (TSTEPS*BATCH)   // 16384

// fp32 output element offsets
static constexpr size_t O_PROBS = 0;
static constexpr size_t O_LOGPA = (size_t)TOK * NACT;   // 2097152
static constexpr size_t O_ENT   = O_LOGPA + TOK;        // 2113536
static constexpr size_t O_VAL   = O_ENT + TOK;          // 2129920
static constexpr size_t O_HT    = O_VAL + TOK;          // 2146304
static constexpr size_t O_CT    = O_HT + (size_t)BATCH * HIDD;  // 2211840

// bf16 weight/activation pool offsets (elements)
static constexpr size_t OX     = 0;
static constexpr size_t OCOVH  = 8388608;
static constexpr size_t OSNW1  = 10485760;
static constexpr size_t OSNW2  = 11010048;
static constexpr size_t OWIH   = 12058624;
static constexpr size_t OWHH   = 16252928;
static constexpr size_t OACW1  = 20447232;
static constexpr size_t OCWW1  = 21495808;
static constexpr size_t OCRW1  = 22544384;
static constexpr size_t OACW2  = 23592960;
static constexpr size_t OCWW2  = 23724032;
static constexpr size_t OCOVW1 = 23855104;
static constexpr size_t OCOVW2 = 23986176;
static constexpr size_t OCRW2  = 24117248;
static constexpr size_t WBUFSZ = 24118272;

using bf16x8 = __attribute__((ext_vector_type(8))) short;
using f32x4  = __attribute__((ext_vector_type(4))) float;

// ---------------- device buffers (all resolved in device code) ----------------
__device__ __align__(16) unsigned short g_wbuf[WBUFSZ];
__device__ __align__(16) unsigned short g_hid1[(size_t)TOK*HIDD];
__device__ __align__(16) unsigned short g_hid [(size_t)TOK*HIDD];
__device__ __align__(16) float          g_xgf [(size_t)TOK*4*HIDD];
__device__ __align__(16) unsigned short g_hidden[(size_t)TOK*HIDD];
__device__ __align__(16) unsigned short g_t3[(size_t)3*TOK*HIDD];
__device__ __align__(16) unsigned short g_aco[(size_t)TOK*NACT];
__device__ __align__(16) unsigned short g_cwo[(size_t)TOK*NACT];
__device__ __align__(16) unsigned short g_covo[(size_t)TOK*NACT];
__device__ __align__(16) unsigned short g_hping[2][BATCH*HIDD];
__device__ float g_val[TOK];             // staged value (fp32)
__device__ float g_ht[BATCH*HIDD];       // staged hT   (fp32)
__device__ float g_ct[BATCH*HIDD];       // staged cT   (fp32)
__device__ int g_isf32;
__device__ unsigned g_bar;
__device__ unsigned g_gen;

__device__ __forceinline__ unsigned short* dev_buf(int id){
  switch(id){
    case 1:  return g_hid1;
    case 2:  return g_hid;
    case 3:  return g_hidden;
    case 4:  return g_t3;
    case 5:  return g_aco;
    case 6:  return g_cwo;
    case 7:  return g_covo;
    case 8:  return (unsigned short*)g_xgf;
    case 9:  return g_t3 + (size_t)TOK*HIDD;
    case 10: return g_t3 + (size_t)2*TOK*HIDD;
    case 11: return g_wbuf + OX;
    case 12: return g_wbuf + OCOVH;
    case 13: return g_wbuf + OSNW1;
    case 14: return g_wbuf + OSNW2;
    case 15: return g_wbuf + OWIH;
    case 16: return g_wbuf + OWHH;
    case 17: return g_wbuf + OACW1;
    case 18: return g_wbuf + OCWW1;
    case 19: return g_wbuf + OCRW1;
    case 20: return g_wbuf + OACW2;
    case 21: return g_wbuf + OCWW2;
    case 22: return g_wbuf + OCOVW1;
    case 23: return g_wbuf + OCOVW2;
    case 24: return g_wbuf + OCRW2;
    default: return nullptr;
  }
}

// ---------------- helpers ----------------
__device__ __forceinline__ float b2f(unsigned short u){
  unsigned int x = ((unsigned int)u) << 16;
  return __builtin_bit_cast(float, x);
}
__device__ __forceinline__ unsigned short f2b(float f){
  unsigned int u = __builtin_bit_cast(unsigned int, f);
  u += 0x7FFFu + ((u >> 16) & 1u);
  return (unsigned short)(u >> 16);
}
__device__ __forceinline__ float ldmix(const void* p, size_t i){
  return g_isf32 ? ((const float*)p)[i] : b2f(((const unsigned short*)p)[i]);
}
__device__ __forceinline__ float sigm(float x){ return 1.f/(1.f + __expf(-x)); }
__device__ __forceinline__ float tanh_f(float x){ float e = __expf(2.f*x); return 1.f - 2.f/(e + 1.f); }

__device__ __forceinline__ void gld16(const unsigned short* g, unsigned short* l){
  __builtin_amdgcn_global_load_lds(
      (__attribute__((address_space(1))) void*)(uintptr_t)g,
      (__attribute__((address_space(3))) void*)l,
      16, 0, 0);
}

// ---------------- dtype detect (hedge; expected fp32 -> g_isf32=1) ----------------
__global__ __launch_bounds__(256) void detect_dtype(const unsigned short* x){
  __shared__ int cnt;
  if (threadIdx.x == 0) cnt = 0;
  __syncthreads();
  int c = 0;
  for (int i = threadIdx.x; i < 4096; i += 256){
    float f = b2f(x[2*i]);       // low half of fp32 if input is fp32
    if (!(fabsf(f) < 1e10f)) c++;
  }
  atomicAdd(&cnt, c);
  __syncthreads();
  if (threadIdx.x == 0) g_isf32 = (cnt > 64) ? 1 : 0;
}

// ---------------- convert 14 arrays into g_wbuf (bf16) ----------------
__global__ __launch_bounds__(256) void cvt_all(
    const void* s0, const void* s1, const void* s2, const void* s3,
    const void* s4, const void* s5, const void* s6, const void* s7,
    const void* s8, const void* s9, const void* s10, const void* s11,
    const void* s12, const void* s13)
{
  const void* src; size_t off; int n;
  switch (blockIdx.y){
    case 0:  src=s0;  off=OX;     n=TOK*OBSD;  break;
    case 1:  src=s1;  off=OCOVH;  n=TOK*NACT;  break;
    case 2:  src=s2;  off=OSNW1;  n=HIDD*OBSD; break;
    case 3:  src=s3;  off=OSNW2;  n=HIDD*HIDD; break;
    case 4:  src=s4;  off=OWIH;   n=4*HIDD*HIDD; break;
    case 5:  src=s5;  off=OWHH;   n=4*HIDD*HIDD; break;
    case 6:  src=s6;  off=OACW1;  n=HIDD*HIDD; break;
    case 7:  src=s7;  off=OCWW1;  n=HIDD*HIDD; break;
    case 8:  src=s8;  off=OCRW1;  n=HIDD*HIDD; break;
    case 9:  src=s9;  off=OACW2;  n=NACT*HIDD; break;
    case 10: src=s10; off=OCWW2;  n=NACT*HIDD; break;
    case 11: src=s11; off=OCOVW1; n=HIDD*NACT; break;
    case 12: src=s12; off=OCOVW2; n=NACT*HIDD; break;
    default: src=s13; off=OCRW2;  n=HIDD;      break;
  }
  const bool f32 = (g_isf32 != 0);
  unsigned short* dst = g_wbuf + off;
  const int stride = gridDim.x * 256;
  for (int i = blockIdx.x*256 + threadIdx.x; i < n; i += stride){
    float v = f32 ? ((const float*)src)[i] : b2f(((const unsigned short*)src)[i]);
    dst[i] = f2b(v);
  }
}

// ---------------- tiled MFMA GEMM: C = act(A[M,K] @ W[N,K]^T + b1 + b2) ----------------
__global__ __launch_bounds__(256) void gemm_bt(
    int a_id, int lda, int w_id, int K,
    const void* __restrict__ b1, const void* __restrict__ b2,
    int c_id, int ldc, int act, int cmode)
{
  __shared__ unsigned short sA[128*32];
  __shared__ unsigned short sB[128*32];
  const unsigned short* A = dev_buf(a_id);
  const unsigned short* W = dev_buf(w_id);
  void* C = dev_buf(c_id);

  const int tid  = threadIdx.x;
  const int wv   = tid >> 6, ln = tid & 63;
  const int quad = ln >> 4, l16 = ln & 15;
  const long bm = (long)blockIdx.y * 128, bn = (long)blockIdx.x * 128;
  const int wr = (wv >> 1) * 64, wc = (wv & 1) * 64;

  const f32x4 zf = {0.f, 0.f, 0.f, 0.f};
  f32x4 acc[4][4];
#pragma unroll
  for (int i = 0; i < 4; i++)
#pragma unroll
    for (int j = 0; j < 4; j++) acc[i][j] = zf;

  const int srow = wv*32 + (ln >> 2);
  const int scol = (ln & 3) * 8;
  const unsigned short* gA = A + (bm + srow)*(long)lda + scol;
  const unsigned short* gB = W + (bn + srow)*(long)K   + scol;
  unsigned short* lA = &sA[(wv*32)*32];
  unsigned short* lB = &sB[(wv*32)*32];

  for (int k0 = 0; k0 < K; k0 += 32){
    __syncthreads();
    gld16(gA + k0,                 lA);
    gld16(gA + k0 + 16*(long)lda,  lA + 16*32);
    gld16(gB + k0,                 lB);
    gld16(gB + k0 + 16*(long)K,    lB + 16*32);
    __syncthreads();
    bf16x8 af[4], bfr[4];
#pragma unroll
    for (int i = 0; i < 4; i++) af[i]  = *(const bf16x8*)&sA[(wr + 16*i + l16)*32 + quad*8];
#pragma unroll
    for (int j = 0; j < 4; j++) bfr[j] = *(const bf16x8*)&sB[(wc + 16*j + l16)*32 + quad*8];
#pragma unroll
    for (int i = 0; i < 4; i++)
#pragma unroll
      for (int j = 0; j < 4; j++)
        acc[i][j] = __builtin_amdgcn_mfma_f32_16x16x32_bf16(af[i], bfr[j], acc[i][j], 0, 0, 0);
  }

#pragma unroll
  for (int j = 0; j < 4; j++){
    const long col = bn + wc + 16*j + l16;
    float bb = (b1 ? ldmix(b1, col) : 0.f) + (b2 ? ldmix(b2, col) : 0.f);
#pragma unroll
    for (int i = 0; i < 4; i++){
#pragma unroll
      for (int r = 0; r < 4; r++){
        const long row = bm + wr + 16*i + quad*4 + r;   // C/D: col=lane&15, row=quad*4+reg
        float v = acc[i][j][r] + bb;
        if (act) v = tanh_f(v);
        if (cmode) ((float*)C)[row*(long)ldc + col] = v;
        else ((unsigned short*)C)[row*(long)ldc + col] = f2b(v);
      }
    }
  }
}

// ---------------- grid barrier (64 WGs co-resident; device-scope coherent) ----------------
__device__ __forceinline__ void grid_barrier(){
  __syncthreads();
  if (threadIdx.x == 0){
    __threadfence();
    unsigned gen = __hip_atomic_load(&g_gen, __ATOMIC_RELAXED, __HIP_MEMORY_SCOPE_AGENT);
    unsigned arr = __hip_atomic_fetch_add(&g_bar, 1u, __ATOMIC_ACQ_REL, __HIP_MEMORY_SCOPE_AGENT);
    if (arr == gridDim.x - 1){
      __hip_atomic_store(&g_bar, 0u, __ATOMIC_RELAXED, __HIP_MEMORY_SCOPE_AGENT);
      __hip_atomic_fetch_add(&g_gen, 1u, __ATOMIC_ACQ_REL, __HIP_MEMORY_SCOPE_AGENT);
    } else {
      while (__hip_atomic_load(&g_gen, __ATOMIC_ACQUIRE, __HIP_MEMORY_SCOPE_AGENT) == gen)
        __builtin_amdgcn_s_sleep(2);
    }
  }
  __syncthreads();
}

// ---------------- persistent LSTM scan: 64 WGs, WG g owns h columns [16g,16g+16) ----------------
__global__ __launch_bounds__(256) void lstm_scan(
    const void* __restrict__ done_p,
    const void* __restrict__ h0_p,
    const void* __restrict__ c0_p)
{
  const int tid  = threadIdx.x;
  const int wv   = tid >> 6, ln = tid & 63;
  const int quad = ln >> 4, l16 = ln & 15;
  const int col0 = blockIdx.x * 16;
  const unsigned short* whh = g_wbuf + OWHH;

  __shared__ float sP[4][BATCH*16];
  __shared__ float sc[BATCH*16];
  __shared__ float sdm[BATCH];

  for (int e = tid; e < BATCH*16; e += 256){
    int row = e >> 4, col = e & 15;
    g_hping[0][row*HIDD + col0 + col] = f2b(ldmix(h0_p, row*HIDD + col0 + col));
    sc[e] = ldmix(c0_p, row*HIDD + col0 + col);
  }
  __threadfence();
  grid_barrier();

  const unsigned short* wrow = &whh[(size_t)(wv*HIDD + col0 + l16) * HIDD];
  const f32x4 zf = {0.f, 0.f, 0.f, 0.f};
  const bf16x8 zb = {0,0,0,0,0,0,0,0};

  for (int s = 0; s < TSTEPS; s++){
    const unsigned short* hb = g_hping[s & 1];
    if (tid < BATCH) sdm[tid] = ldmix(done_p, s*BATCH + tid);
    __syncthreads();
    bool dz[4];
#pragma unroll
    for (int rt = 0; rt < 4; rt++) dz[rt] = (sdm[16*rt + l16] != 0.f);

    f32x4 acc[4];
#pragma unroll
    for (int rt = 0; rt < 4; rt++) acc[rt] = zf;

    for (int k0 = 0; k0 < HIDD; k0 += 32){
      const int k = k0 + quad*8;
      bf16x8 bfrag = *(const bf16x8*)&wrow[k];
#pragma unroll
      for (int rt = 0; rt < 4; rt++){
        bf16x8 afrag = *(const bf16x8*)&hb[(size_t)(16*rt + l16)*HIDD + k];
        if (dz[rt]) afrag = zb;
        acc[rt] = __builtin_amdgcn_mfma_f32_16x16x32_bf16(afrag, bfrag, acc[rt], 0, 0, 0);
      }
    }
#pragma unroll
    for (int rt = 0; rt < 4; rt++)
#pragma unroll
      for (int r = 0; r < 4; r++)
        sP[wv][(16*rt + quad*4 + r)*16 + l16] = acc[rt][r];
    __syncthreads();

    const bool last = (s == TSTEPS-1);
    for (int e = tid; e < BATCH*16; e += 256){
      int row = e >> 4, col = e & 15;
      int token = s*BATCH + row;
      int gc = col0 + col;
      const float* xr = &g_xgf[(size_t)token*4*HIDD];
      float iv = sigm (sP[0][e] + xr[gc]);
      float fv = sigm (sP[1][e] + xr[HIDD   + gc]);
      float gv = tanh_f(sP[2][e] + xr[2*HIDD + gc]);
      float ov = sigm (sP[3][e] + xr[3*HIDD + gc]);
      float cp = (sdm[row] != 0.f) ? 0.f : sc[e];
      float c  = fv*cp + iv*gv;
      float h  = ov * tanh_f(c);
      sc[e] = c;
      unsigned short h16 = f2b(h);
      g_hping[(s+1)&1][row*HIDD + gc] = h16;
      g_hidden[(size_t)token*HIDD + gc] = h16;
      if (last){
        g_ht[row*HIDD + gc] = h;   // staged fp32
        g_ct[row*HIDD + gc] = c;
      }
    }
    __threadfence();
    grid_barrier();
  }
}

// ---------------- value head: wave-per-row dot over cr slice (staged fp32) ----------------
__global__ __launch_bounds__(256) void rowdot_kernel(const void* __restrict__ b)
{
  const unsigned short* A = g_t3 + (size_t)2*TOK*HIDD;
  const unsigned short* w = g_wbuf + OCRW2;
  int row = blockIdx.x*4 + (threadIdx.x >> 6);
  int ln  = threadIdx.x & 63;
  float s = 0.f;
  for (int k = ln*8; k < HIDD; k += 512){
    bf16x8 av = *(const bf16x8*)&A[(size_t)row*HIDD + k];
    bf16x8 wv = *(const bf16x8*)&w[k];
#pragma unroll
    for (int j = 0; j < 8; j++) s += b2f((unsigned short)av[j]) * b2f((unsigned short)wv[j]);
  }
  for (int o = 32; o; o >>= 1) s += __shfl_xor(s, o, 64);
  if (ln == 0) g_val[row] = s + ldmix(b, 0);
}

// ---------------- FINALIZE: the ONLY writer of d_out (fp32); covers every element ----------------
__global__ __launch_bounds__(256) void finalize(
    const int* __restrict__ action, float* __restrict__ dout)
{
  int row = blockIdx.x*4 + (threadIdx.x >> 6);
  int ln  = threadIdx.x & 63;
  size_t base = (size_t)row * NACT;
  float l0 = b2f(g_aco[base+ln])    + b2f(g_cwo[base+ln])   *b2f(g_covo[base+ln]);
  float l1 = b2f(g_aco[base+64+ln]) + b2f(g_cwo[base+64+ln])*b2f(g_covo[base+64+ln]);
  float mx = fmaxf(l0, l1);
  for (int o = 32; o; o >>= 1) mx = fmaxf(mx, __shfl_xor(mx, o, 64));
  float e0 = __expf(l0 - mx), e1 = __expf(l1 - mx);
  float sm = e0 + e1;
  for (int o = 32; o; o >>= 1) sm += __shfl_xor(sm, o, 64);
  float inv = 1.f/sm, ls = __logf(sm);
  float p0 = e0*inv, p1 = e1*inv;
  float lp0 = l0 - mx - ls, lp1 = l1 - mx - ls;
  dout[O_PROBS + base + ln]      = p0;
  dout[O_PROBS + base + 64 + ln] = p1;
  float ent = -(p0*lp0 + p1*lp1);
  for (int o = 32; o; o >>= 1) ent += __shfl_xor(ent, o, 64);
  int a = action[row];
  float lpa = (a == ln) ? lp0 : (a == ln + 64) ? lp1 : 0.f;
  for (int o = 32; o; o >>= 1) lpa += __shfl_xor(lpa, o, 64);
  if (ln == 0){
    dout[O_LOGPA + row] = lpa;
    dout[O_ENT   + row] = ent;
  }
  // staged small outputs: full coverage (1,048,576 threads >= all regions)
  int gtid = blockIdx.x*256 + threadIdx.x;
  if (gtid < TOK)        dout[O_VAL + gtid] = g_val[gtid];
  if (gtid < BATCH*HIDD){
    dout[O_HT + gtid] = g_ht[gtid];
    dout[O_CT + gtid] = g_ct[gtid];
  }
}

// ---------------- host ----------------
extern "C" void kernel_launch(void* const* d_in, const int* in_sizes, int n_in,
                              void* d_out, int out_size, void* d_ws, size_t ws_size,
                              hipStream_t stream)
{
  (void)in_sizes; (void)n_in; (void)out_size; (void)d_ws; (void)ws_size;
  float* dout = (float*)d_out;

  hipLaunchKernelGGL(detect_dtype, dim3(1), dim3(256), 0, stream,
                     (const unsigned short*)d_in[0]);

  hipLaunchKernelGGL(cvt_all, dim3(512, 14), dim3(256), 0, stream,
                     d_in[0], d_in[2], d_in[6], d_in[8], d_in[10], d_in[11],
                     d_in[18], d_in[26], d_in[14], d_in[20], d_in[28],
                     d_in[22], d_in[24], d_in[16]);

  auto gemm = [&](int a_id, int lda, int w_id, int K,
                  const void* b1, const void* b2,
                  int c_id, int ldc, int N, int act, int cmode){
    hipLaunchKernelGGL(gemm_bt, dim3(N/128, TOK/128), dim3(256), 0, stream,
                       a_id, lda, w_id, K, b1, b2, c_id, ldc, act, cmode);
  };

  // perception MLP + hoisted input-gate GEMM
  gemm(11, OBSD, 13, OBSD, d_in[7],  nullptr,  1, HIDD,   HIDD,   1, 0);
  gemm(1,  HIDD, 14, HIDD, d_in[9],  nullptr,  2, HIDD,   HIDD,   1, 0);
  gemm(2,  HIDD, 15, HIDD, d_in[12], d_in[13], 8, 4*HIDD, 4*HIDD, 0, 1);

  // sequential LSTM scan (persistent, 64 WGs, 1 grid barrier/step)
  hipLaunchKernelGGL(lstm_scan, dim3(64), dim3(256), 0, stream,
                     d_in[1], d_in[3], d_in[4]);

  // heads
  gemm(3,  HIDD, 17, HIDD, d_in[19], nullptr, 4,  HIDD, HIDD, 1, 0);
  gemm(3,  HIDD, 18, HIDD, d_in[27], nullptr, 9,  HIDD, HIDD, 1, 0);
  gemm(3,  HIDD, 19, HIDD, d_in[15], nullptr, 10, HIDD, HIDD, 1, 0);
  gemm(4,  HIDD, 20, HIDD, d_in[21], nullptr, 5,  NACT, NACT, 0, 0);
  gemm(9,  HIDD, 21, HIDD, d_in[29], nullptr, 6,  NACT, NACT, 0, 0);
  gemm(12, NACT, 22, NACT, d_in[23], nullptr, 1,  HIDD, HIDD, 1, 0);
  gemm(1,  HIDD, 23, HIDD, d_in[25], nullptr, 7,  NACT, NACT, 0, 0);

  // value head (staged)
  hipLaunchKernelGGL(rowdot_kernel, dim3(TOK/4), dim3(256), 0, stream, d_in[17]);

  // single final writer of d_out — covers all out_size fp32 elements
  hipLaunchKernelGGL(finalize, dim3(TOK/4), dim3(256), 0, stream,
                     (const int*)d_in[5], dout);
}

// Round 6
// 4947.227 us; speedup vs baseline: 1.8852x; 1.8852x over previous
//
#include <hip/hip_runtime.h>
#include <cstdint>
#include <cstddef>

// ---------------- problem dims ----------------
#define TSTEPS 256
#define BATCH  64
#define OBSD   512
#define HIDD   1024
#define NACT   128
#define TOK    (TSTEPS*BATCH)   // 16384

// fp32 output element offsets
static constexpr size_t O_PROBS = 0;
static constexpr size_t O_LOGPA = (size_t)TOK * NACT;
static constexpr size_t O_ENT   = O_LOGPA + TOK;
static constexpr size_t O_VAL   = O_ENT + TOK;
static constexpr size_t O_HT    = O_VAL + TOK;
static constexpr size_t O_CT    = O_HT + (size_t)BATCH * HIDD;

// bf16 weight/activation pool offsets (elements)
static constexpr size_t OX     = 0;
static constexpr size_t OCOVH  = 8388608;
static constexpr size_t OSNW1  = 10485760;
static constexpr size_t OSNW2  = 11010048;
static constexpr size_t OWIH   = 12058624;
static constexpr size_t OWHH   = 16252928;
static constexpr size_t OACW1  = 20447232;   // ac|cw|cr contiguous -> one N=3072 GEMM
static constexpr size_t OCWW1  = 21495808;
static constexpr size_t OCRW1  = 22544384;
static constexpr size_t OACW2  = 23592960;
static constexpr size_t OCWW2  = 23724032;
static constexpr size_t OCOVW1 = 23855104;
static constexpr size_t OCOVW2 = 23986176;
static constexpr size_t OCRW2  = 24117248;
static constexpr size_t WBUFSZ = 24118272;

using bf16x8 = __attribute__((ext_vector_type(8))) short;
using f32x4  = __attribute__((ext_vector_type(4))) float;

// ---------------- device buffers (all resolved in device code) ----------------
__device__ __align__(16) unsigned short g_wbuf[WBUFSZ];
__device__ __align__(16) unsigned short g_hid1[(size_t)TOK*HIDD];
__device__ __align__(16) unsigned short g_hid [(size_t)TOK*HIDD];
__device__ __align__(16) float          g_xgf [(size_t)TOK*4*HIDD];
__device__ __align__(16) unsigned short g_hid2[(size_t)64*TOK*16];   // blocked hidden [cb][token][16]
__device__ __align__(16) unsigned short g_t3[(size_t)TOK*3*HIDD];    // [TOK][3072] ac|cw|cr
__device__ __align__(16) unsigned short g_aco[(size_t)TOK*NACT];
__device__ __align__(16) unsigned short g_cwo[(size_t)TOK*NACT];
__device__ __align__(16) unsigned short g_covo[(size_t)TOK*NACT];
__device__ __align__(16) unsigned short g_hp2[2*64*1024];            // blocked h ping-pong [buf][cb][row][16]
__device__ float g_val[TOK];
__device__ float g_ht[BATCH*HIDD];
__device__ float g_ct[BATCH*HIDD];
__device__ int g_isf32;
__device__ unsigned g_bar;
__device__ unsigned g_gen;

__device__ __forceinline__ unsigned short* dev_buf(int id){
  switch(id){
    case 1:  return g_hid1;
    case 2:  return g_hid;
    case 3:  return g_hid2;
    case 4:  return g_t3;
    case 5:  return g_aco;
    case 6:  return g_cwo;
    case 7:  return g_covo;
    case 8:  return (unsigned short*)g_xgf;
    case 9:  return g_t3 + 1024;          // cw slice (row-interleaved, lda 3072)
    case 10: return g_t3 + 2048;          // cr slice
    case 11: return g_wbuf + OX;
    case 12: return g_wbuf + OCOVH;
    case 13: return g_wbuf + OSNW1;
    case 14: return g_wbuf + OSNW2;
    case 15: return g_wbuf + OWIH;
    case 16: return g_wbuf + OWHH;
    case 17: return g_wbuf + OACW1;       // 3072-row fused head weight
    case 20: return g_wbuf + OACW2;
    case 21: return g_wbuf + OCWW2;
    case 22: return g_wbuf + OCOVW1;
    case 23: return g_wbuf + OCOVW2;
    case 24: return g_wbuf + OCRW2;
    default: return nullptr;
  }
}

// ---------------- helpers ----------------
__device__ __forceinline__ float b2f(unsigned short u){
  unsigned int x = ((unsigned int)u) << 16;
  return __builtin_bit_cast(float, x);
}
__device__ __forceinline__ unsigned short f2b(float f){
  unsigned int u = __builtin_bit_cast(unsigned int, f);
  u += 0x7FFFu + ((u >> 16) & 1u);
  return (unsigned short)(u >> 16);
}
__device__ __forceinline__ float ldmix(const void* p, size_t i){
  return g_isf32 ? ((const float*)p)[i] : b2f(((const unsigned short*)p)[i]);
}
__device__ __forceinline__ float sigm(float x){ return 1.f/(1.f + __expf(-x)); }
__device__ __forceinline__ float tanh_f(float x){ float e = __expf(2.f*x); return 1.f - 2.f/(e + 1.f); }

__device__ __forceinline__ void gld16(const unsigned short* g, unsigned short* l){
  __builtin_amdgcn_global_load_lds(
      (__attribute__((address_space(1))) void*)(uintptr_t)g,
      (__attribute__((address_space(3))) void*)l,
      16, 0, 0);
}

// ---------------- dtype detect ----------------
__global__ __launch_bounds__(256) void detect_dtype(const unsigned short* x){
  __shared__ int cnt;
  if (threadIdx.x == 0) cnt = 0;
  __syncthreads();
  int c = 0;
  for (int i = threadIdx.x; i < 4096; i += 256){
    float f = b2f(x[2*i]);
    if (!(fabsf(f) < 1e10f)) c++;
  }
  atomicAdd(&cnt, c);
  __syncthreads();
  if (threadIdx.x == 0) g_isf32 = (cnt > 64) ? 1 : 0;
}

// ---------------- convert 14 arrays into g_wbuf (bf16) ----------------
__global__ __launch_bounds__(256) void cvt_all(
    const void* s0, const void* s1, const void* s2, const void* s3,
    const void* s4, const void* s5, const void* s6, const void* s7,
    const void* s8, const void* s9, const void* s10, const void* s11,
    const void* s12, const void* s13)
{
  const void* src; size_t off; int n;
  switch (blockIdx.y){
    case 0:  src=s0;  off=OX;     n=TOK*OBSD;  break;
    case 1:  src=s1;  off=OCOVH;  n=TOK*NACT;  break;
    case 2:  src=s2;  off=OSNW1;  n=HIDD*OBSD; break;
    case 3:  src=s3;  off=OSNW2;  n=HIDD*HIDD; break;
    case 4:  src=s4;  off=OWIH;   n=4*HIDD*HIDD; break;
    case 5:  src=s5;  off=OWHH;   n=4*HIDD*HIDD; break;
    case 6:  src=s6;  off=OACW1;  n=HIDD*HIDD; break;
    case 7:  src=s7;  off=OCWW1;  n=HIDD*HIDD; break;
    case 8:  src=s8;  off=OCRW1;  n=HIDD*HIDD; break;
    case 9:  src=s9;  off=OACW2;  n=NACT*HIDD; break;
    case 10: src=s10; off=OCWW2;  n=NACT*HIDD; break;
    case 11: src=s11; off=OCOVW1; n=HIDD*NACT; break;
    case 12: src=s12; off=OCOVW2; n=NACT*HIDD; break;
    default: src=s13; off=OCRW2;  n=HIDD;      break;
  }
  const bool f32 = (g_isf32 != 0);
  unsigned short* dst = g_wbuf + off;
  const int stride = gridDim.x * 256;
  for (int i = blockIdx.x*256 + threadIdx.x; i < n; i += stride){
    float v = f32 ? ((const float*)src)[i] : b2f(((const unsigned short*)src)[i]);
    dst[i] = f2b(v);
  }
}

// ---------------- tiled MFMA GEMM: C = act(A @ W^T + bias) ----------------
// ablk: A is blocked [cb][row][16] (g_hid2). bmode: 3-way bias select by col/1024.
__global__ __launch_bounds__(256) void gemm_bt(
    int a_id, int lda, int ablk, int w_id, int K,
    const void* __restrict__ b1, const void* __restrict__ b2, const void* __restrict__ b3,
    int bmode, int c_id, int ldc, int act, int cmode)
{
  __shared__ unsigned short sA[128*32];
  __shared__ unsigned short sB[128*32];
  const unsigned short* A = dev_buf(a_id);
  const unsigned short* W = dev_buf(w_id);
  void* C = dev_buf(c_id);

  const int tid  = threadIdx.x;
  const int wv   = tid >> 6, ln = tid & 63;
  const int quad = ln >> 4, l16 = ln & 15;
  const long bm = (long)blockIdx.y * 128, bn = (long)blockIdx.x * 128;
  const int wr = (wv >> 1) * 64, wc = (wv & 1) * 64;

  const f32x4 zf = {0.f, 0.f, 0.f, 0.f};
  f32x4 acc[4][4];
#pragma unroll
  for (int i = 0; i < 4; i++)
#pragma unroll
    for (int j = 0; j < 4; j++) acc[i][j] = zf;

  const int srow = wv*32 + (ln >> 2);
  const int scol = (ln & 3) * 8;
  const unsigned short* gA = A + (bm + srow)*(long)lda + scol;
  const unsigned short* gB = W + (bn + srow)*(long)K   + scol;
  unsigned short* lA = &sA[(wv*32)*32];
  unsigned short* lB = &sB[(wv*32)*32];

  for (int k0 = 0; k0 < K; k0 += 32){
    __syncthreads();
    if (ablk){
      const int kk = k0 + scol;
      const long cbase = (long)(kk >> 4) * ((long)TOK*16) + (kk & 15);
      gld16(A + cbase + (bm + srow)*16,      lA);
      gld16(A + cbase + (bm + srow + 16)*16, lA + 16*32);
    } else {
      gld16(gA + k0,                lA);
      gld16(gA + k0 + 16*(long)lda, lA + 16*32);
    }
    gld16(gB + k0,               lB);
    gld16(gB + k0 + 16*(long)K,  lB + 16*32);
    __syncthreads();
    bf16x8 af[4], bfr[4];
#pragma unroll
    for (int i = 0; i < 4; i++) af[i]  = *(const bf16x8*)&sA[(wr + 16*i + l16)*32 + quad*8];
#pragma unroll
    for (int j = 0; j < 4; j++) bfr[j] = *(const bf16x8*)&sB[(wc + 16*j + l16)*32 + quad*8];
#pragma unroll
    for (int i = 0; i < 4; i++)
#pragma unroll
      for (int j = 0; j < 4; j++)
        acc[i][j] = __builtin_amdgcn_mfma_f32_16x16x32_bf16(af[i], bfr[j], acc[i][j], 0, 0, 0);
  }

#pragma unroll
  for (int j = 0; j < 4; j++){
    const long col = bn + wc + 16*j + l16;
    float bb;
    if (bmode){
      const void* bp = (col < 1024) ? b1 : (col < 2048) ? b2 : b3;
      bb = ldmix(bp, col & 1023);
    } else {
      bb = (b1 ? ldmix(b1, col) : 0.f) + (b2 ? ldmix(b2, col) : 0.f);
    }
#pragma unroll
    for (int i = 0; i < 4; i++){
#pragma unroll
      for (int r = 0; r < 4; r++){
        const long row = bm + wr + 16*i + quad*4 + r;   // C/D: col=lane&15, row=quad*4+reg
        float v = acc[i][j][r] + bb;
        if (act) v = tanh_f(v);
        if (cmode) ((float*)C)[row*(long)ldc + col] = v;
        else ((unsigned short*)C)[row*(long)ldc + col] = f2b(v);
      }
    }
  }
}

// ---------------- grid barrier (64 WGs co-resident; device-scope coherent) ----------------
__device__ __forceinline__ void grid_barrier(){
  __syncthreads();
  if (threadIdx.x == 0){
    __threadfence();
    unsigned gen = __hip_atomic_load(&g_gen, __ATOMIC_RELAXED, __HIP_MEMORY_SCOPE_AGENT);
    unsigned arr = __hip_atomic_fetch_add(&g_bar, 1u, __ATOMIC_ACQ_REL, __HIP_MEMORY_SCOPE_AGENT);
    if (arr == gridDim.x - 1){
      __hip_atomic_store(&g_bar, 0u, __ATOMIC_RELAXED, __HIP_MEMORY_SCOPE_AGENT);
      __hip_atomic_fetch_add(&g_gen, 1u, __ATOMIC_ACQ_REL, __HIP_MEMORY_SCOPE_AGENT);
    } else {
      while (__hip_atomic_load(&g_gen, __ATOMIC_ACQUIRE, __HIP_MEMORY_SCOPE_AGENT) == gen)
        __builtin_amdgcn_s_sleep(1);
    }
  }
  __syncthreads();
}

// ---------------- persistent LSTM scan ----------------
// 64 WGs; WG cb owns h cols [16cb,16cb+16). Per step: stage FULL h (128KB) into LDS once
// (shared by all 4 waves), w_hh fragments live in 128 VGPRs, producer-side done masking,
// coalesced blocked writes. One grid barrier per step.
__global__ __launch_bounds__(256, 1) void lstm_scan(
    const void* __restrict__ done_p,
    const void* __restrict__ h0_p,
    const void* __restrict__ c0_p)
{
  __shared__ unsigned short sH[64*1024];   // 128 KB, chunk-XOR swizzled
  __shared__ float sP[4][64*17];           // 17 KB, padded

  const int tid  = threadIdx.x;
  const int wv   = tid >> 6, ln = tid & 63;
  const int quad = ln >> 4, l16 = ln & 15;
  const int cb   = blockIdx.x;
  const int col0 = cb * 16;
  const int grow = tid >> 2;           // gate-phase row (thread owns els 4t..4t+3)
  const int gcol = (tid & 3) * 4;

  // cell state lives in registers (thread t owns (grow, gcol..gcol+3) forever)
  float cst[4];
#pragma unroll
  for (int j = 0; j < 4; j++) cst[j] = ldmix(c0_p, grow*HIDD + col0 + gcol + j);

  // h0 -> blocked ping buffer (own block), masked by done[0]
  for (int e = tid; e < 1024; e += 256){
    int row = e >> 4, col = e & 15;
    float d0 = ldmix(done_p, row);
    float h0 = (d0 != 0.f) ? 0.f : ldmix(h0_p, row*HIDD + col0 + col);
    g_hp2[cb*1024 + e] = f2b(h0);
  }

  // preload w_hh fragments: gate wv, output col col0+l16, k-slice quad*8 of each 32
  const unsigned short* wrow = g_wbuf + OWHH + (size_t)(wv*HIDD + col0 + l16) * HIDD;
  bf16x8 wreg[32];
#pragma unroll
  for (int i = 0; i < 32; i++) wreg[i] = *(const bf16x8*)&wrow[i*32 + quad*8];

  grid_barrier();

  const f32x4 zf = {0.f, 0.f, 0.f, 0.f};
  const int rx0 = l16 & 7;   // row&7 per rt is constant (16rt+l16)

  for (int s = 0; s < TSTEPS; s++){
    const unsigned short* hb = g_hp2 + (s & 1)*65536;
    unsigned short*       hn = g_hp2 + ((s + 1) & 1)*65536;

    // 1) stage full h into LDS (swizzled), 32 x 1KB per wave, per-lane gather addresses
#pragma unroll 8
    for (int i = 0; i < 32; i++){
      int C   = (wv*32 + i)*64 + ln;     // 16B chunk index in sH
      int row = C >> 7;
      int c   = (C & 127) ^ (row & 7);   // source chunk (de-swizzle)
      const unsigned short* src = hb + ((c >> 1)*1024 + row*16 + (c & 1)*8);
      gld16(src, &sH[(size_t)(wv*32 + i)*512]);
    }
    // 2) prefetch step inputs into registers (overlap with staging)
    const int token = s*BATCH + grow;
    const float* xr = &g_xgf[(size_t)token*4096 + col0 + gcol];
    float4 xg0 = *(const float4*)(xr);
    float4 xg1 = *(const float4*)(xr + 1024);
    float4 xg2 = *(const float4*)(xr + 2048);
    float4 xg3 = *(const float4*)(xr + 3072);
    float dcur  = ldmix(done_p, s*BATCH + grow);
    float dnext = (s < TSTEPS-1) ? ldmix(done_p, (s+1)*BATCH + grow) : 0.f;
    __syncthreads();   // drains staging (vmcnt) + syncs LDS

    // 3) MFMA: h (LDS) x w_hh (regs)
    f32x4 acc[4] = {zf, zf, zf, zf};
#pragma unroll
    for (int i = 0; i < 32; i++){
      const int cbase = i*4 + quad;
#pragma unroll
      for (int rt = 0; rt < 4; rt++){
        const int row = 16*rt + l16;
        const int cc = cbase ^ rx0;
        bf16x8 af = *(const bf16x8*)&sH[(size_t)row*1024 + cc*8];
        acc[rt] = __builtin_amdgcn_mfma_f32_16x16x32_bf16(af, wreg[i], acc[rt], 0, 0, 0);
      }
    }
#pragma unroll
    for (int rt = 0; rt < 4; rt++)
#pragma unroll
      for (int r = 0; r < 4; r++)
        sP[wv][(16*rt + quad*4 + r)*17 + l16] = acc[rt][r];
    __syncthreads();

    // 4) gate math (4 els/thread), producer-side done masking for h_next
    const bool last = (s == TSTEPS-1);
    unsigned short hs[4];
#pragma unroll
    for (int j = 0; j < 4; j++){
      const int col = gcol + j;
      const int pw  = grow*17 + col;
      float iv = sigm (sP[0][pw] + ((const float*)&xg0)[j]);
      float fv = sigm (sP[1][pw] + ((const float*)&xg1)[j]);
      float gv = tanh_f(sP[2][pw] + ((const float*)&xg2)[j]);
      float ov = sigm (sP[3][pw] + ((const float*)&xg3)[j]);
      float cp = (dcur != 0.f) ? 0.f : cst[j];
      float c  = fv*cp + iv*gv;
      float h  = ov * tanh_f(c);
      cst[j] = c;
      hs[j] = f2b(h);
      if (last){
        g_ht[grow*HIDD + col0 + col] = h;
        g_ct[grow*HIDD + col0 + col] = c;
      }
    }
    // blocked hidden store (2KB contiguous per WG)
    *(ushort4*)&g_hid2[(size_t)cb*((size_t)TOK*16) + (size_t)token*16 + gcol] = *(const ushort4*)hs;
    // next-h store, pre-masked by done[s+1] (consumer reads clean zeros)
    if (dnext != 0.f){ hs[0]=0; hs[1]=0; hs[2]=0; hs[3]=0; }
    *(ushort4*)&hn[cb*1024 + tid*4] = *(const ushort4*)hs;

    grid_barrier();
  }
}

// ---------------- value head: wave-per-row dot over cr slice of t3 ----------------
__global__ __launch_bounds__(256) void rowdot_kernel(const void* __restrict__ b)
{
  const unsigned short* A = g_t3 + 2048;     // cr cols of [TOK][3072]
  const unsigned short* w = g_wbuf + OCRW2;
  int row = blockIdx.x*4 + (threadIdx.x >> 6);
  int ln  = threadIdx.x & 63;
  float s = 0.f;
  for (int k = ln*8; k < HIDD; k += 512){
    bf16x8 av = *(const bf16x8*)&A[(size_t)row*3072 + k];
    bf16x8 wv = *(const bf16x8*)&w[k];
#pragma unroll
    for (int j = 0; j < 8; j++) s += b2f((unsigned short)av[j]) * b2f((unsigned short)wv[j]);
  }
  for (int o = 32; o; o >>= 1) s += __shfl_xor(s, o, 64);
  if (ln == 0) g_val[row] = s + ldmix(b, 0);
}

// ---------------- FINALIZE: only writer of d_out (fp32), full coverage ----------------
__global__ __launch_bounds__(256) void finalize(
    const int* __restrict__ action, float* __restrict__ dout)
{
  int row = blockIdx.x*4 + (threadIdx.x >> 6);
  int ln  = threadIdx.x & 63;
  size_t base = (size_t)row * NACT;
  float l0 = b2f(g_aco[base+ln])    + b2f(g_cwo[base+ln])   *b2f(g_covo[base+ln]);
  float l1 = b2f(g_aco[base+64+ln]) + b2f(g_cwo[base+64+ln])*b2f(g_covo[base+64+ln]);
  float mx = fmaxf(l0, l1);
  for (int o = 32; o; o >>= 1) mx = fmaxf(mx, __shfl_xor(mx, o, 64));
  float e0 = __expf(l0 - mx), e1 = __expf(l1 - mx);
  float sm = e0 + e1;
  for (int o = 32; o; o >>= 1) sm += __shfl_xor(sm, o, 64);
  float inv = 1.f/sm, ls = __logf(sm);
  float p0 = e0*inv, p1 = e1*inv;
  float lp0 = l0 - mx - ls, lp1 = l1 - mx - ls;
  dout[O_PROBS + base + ln]      = p0;
  dout[O_PROBS + base + 64 + ln] = p1;
  float ent = -(p0*lp0 + p1*lp1);
  for (int o = 32; o; o >>= 1) ent += __shfl_xor(ent, o, 64);
  int a = action[row];
  float lpa = (a == ln) ? lp0 : (a == ln + 64) ? lp1 : 0.f;
  for (int o = 32; o; o >>= 1) lpa += __shfl_xor(lpa, o, 64);
  if (ln == 0){
    dout[O_LOGPA + row] = lpa;
    dout[O_ENT   + row] = ent;
  }
  int gtid = blockIdx.x*256 + threadIdx.x;
  if (gtid < TOK)        dout[O_VAL + gtid] = g_val[gtid];
  if (gtid < BATCH*HIDD){
    dout[O_HT + gtid] = g_ht[gtid];
    dout[O_CT + gtid] = g_ct[gtid];
  }
}

// ---------------- host ----------------
extern "C" void kernel_launch(void* const* d_in, const int* in_sizes, int n_in,
                              void* d_out, int out_size, void* d_ws, size_t ws_size,
                              hipStream_t stream)
{
  (void)in_sizes; (void)n_in; (void)out_size; (void)d_ws; (void)ws_size;
  float* dout = (float*)d_out;

  hipLaunchKernelGGL(detect_dtype, dim3(1), dim3(256), 0, stream,
                     (const unsigned short*)d_in[0]);

  hipLaunchKernelGGL(cvt_all, dim3(512, 14), dim3(256), 0, stream,
                     d_in[0], d_in[2], d_in[6], d_in[8], d_in[10], d_in[11],
                     d_in[18], d_in[26], d_in[14], d_in[20], d_in[28],
                     d_in[22], d_in[24], d_in[16]);

  auto gemm = [&](int a_id, int lda, int ablk, int w_id, int K,
                  const void* b1, const void* b2, const void* b3, int bmode,
                  int c_id, int ldc, int N, int act, int cmode){
    hipLaunchKernelGGL(gemm_bt, dim3(N/128, TOK/128), dim3(256), 0, stream,
                       a_id, lda, ablk, w_id, K, b1, b2, b3, bmode,
                       c_id, ldc, act, cmode);
  };

  // perception MLP + hoisted input-gate GEMM
  gemm(11, OBSD, 0, 13, OBSD, d_in[7],  nullptr, nullptr, 0, 1, HIDD,   HIDD,   1, 0);
  gemm(1,  HIDD, 0, 14, HIDD, d_in[9],  nullptr, nullptr, 0, 2, HIDD,   HIDD,   1, 0);
  gemm(2,  HIDD, 0, 15, HIDD, d_in[12], d_in[13], nullptr, 0, 8, 4*HIDD, 4*HIDD, 0, 1);

  // sequential LSTM scan (persistent, 64 WGs, 1 grid barrier/step)
  hipLaunchKernelGGL(lstm_scan, dim3(64), dim3(256), 0, stream,
                     d_in[1], d_in[3], d_in[4]);

  // fused head hidden GEMM: t3 = tanh(hidden @ [ac|cw|cr]w1^T + b), N=3072, blocked A
  gemm(3, 3072, 1, 17, HIDD, d_in[19], d_in[27], d_in[15], 1, 4, 3*HIDD, 3*HIDD, 1, 0);
  // output heads
  gemm(4,  3072, 0, 20, HIDD, d_in[21], nullptr, nullptr, 0, 5, NACT, NACT, 0, 0);
  gemm(9,  3072, 0, 21, HIDD, d_in[29], nullptr, nullptr, 0, 6, NACT, NACT, 0, 0);
  gemm(12, NACT, 0, 22, NACT, d_in[23], nullptr, nullptr, 0, 1, HIDD, HIDD, 1, 0);
  gemm(1,  HIDD, 0, 23, HIDD, d_in[25], nullptr, nullptr, 0, 7, NACT, NACT, 0, 0);

  // value head (staged)
  hipLaunchKernelGGL(rowdot_kernel, dim3(TOK/4), dim3(256), 0, stream, d_in[17]);

  // single final writer of d_out
  hipLaunchKernelGGL(finalize, dim3(TOK/4), dim3(256), 0, stream,
                     (const int*)d_in[5], dout);
}

// Round 7
// 4481.849 us; speedup vs baseline: 2.0810x; 1.1038x over previous
//
#include <hip/hip_runtime.h>
#include <cstdint>
#include <cstddef>

// ---------------- problem dims ----------------
#define TSTEPS 256
#define BATCH  64
#define OBSD   512
#define HIDD   1024
#define NACT   128
#define TOK    (TSTEPS*BATCH)   // 16384

// fp32 output element offsets
static constexpr size_t O_PROBS = 0;
static constexpr size_t O_LOGPA = (size_t)TOK * NACT;
static constexpr size_t O_ENT   = O_LOGPA + TOK;
static constexpr size_t O_VAL   = O_ENT + TOK;
static constexpr size_t O_HT    = O_VAL + TOK;
static constexpr size_t O_CT    = O_HT + (size_t)BATCH * HIDD;

// bf16 weight/activation pool offsets (elements)
static constexpr size_t OX     = 0;
static constexpr size_t OCOVH  = 8388608;
static constexpr size_t OSNW1  = 10485760;
static constexpr size_t OSNW2  = 11010048;
static constexpr size_t OWIH   = 12058624;
static constexpr size_t OWHH   = 16252928;
static constexpr size_t OACW1  = 20447232;   // ac|cw|cr contiguous -> one N=3072 GEMM
static constexpr size_t OCWW1  = 21495808;
static constexpr size_t OCRW1  = 22544384;
static constexpr size_t OACW2  = 23592960;
static constexpr size_t OCWW2  = 23724032;
static constexpr size_t OCOVW1 = 23855104;
static constexpr size_t OCOVW2 = 23986176;
static constexpr size_t OCRW2  = 24117248;
static constexpr size_t WBUFSZ = 24118272;

using bf16x8 = __attribute__((ext_vector_type(8))) short;
using f32x4  = __attribute__((ext_vector_type(4))) float;

// ---------------- device buffers (all resolved in device code) ----------------
__device__ __align__(16) unsigned short g_wbuf[WBUFSZ];
__device__ __align__(16) unsigned short g_hid1[(size_t)TOK*HIDD];
__device__ __align__(16) unsigned short g_hid [(size_t)TOK*HIDD];
__device__ __align__(16) float          g_xgf [(size_t)TOK*4*HIDD];
__device__ __align__(16) unsigned short g_hid2[(size_t)64*TOK*16];   // blocked hidden [cb][token][16]
__device__ __align__(16) unsigned short g_t3[(size_t)TOK*3*HIDD];    // [TOK][3072] ac|cw|cr
__device__ __align__(16) unsigned short g_aco[(size_t)TOK*NACT];
__device__ __align__(16) unsigned short g_cwo[(size_t)TOK*NACT];
__device__ __align__(16) unsigned short g_covo[(size_t)TOK*NACT];
__device__ __align__(16) unsigned short g_hp2[2*64*1024];            // blocked h ping-pong [buf][cb][row][16]
__device__ float g_val[TOK];
__device__ float g_ht[BATCH*HIDD];
__device__ float g_ct[BATCH*HIDD];
__device__ int g_isf32;
__device__ unsigned g_grp[8];   // two-level barrier: group counters
__device__ unsigned g_root;
__device__ unsigned g_gen;

__device__ __forceinline__ unsigned short* dev_buf(int id){
  switch(id){
    case 1:  return g_hid1;
    case 2:  return g_hid;
    case 3:  return g_hid2;
    case 4:  return g_t3;
    case 5:  return g_aco;
    case 6:  return g_cwo;
    case 7:  return g_covo;
    case 8:  return (unsigned short*)g_xgf;
    case 9:  return g_t3 + 1024;          // cw slice (row-interleaved, lda 3072)
    case 10: return g_t3 + 2048;          // cr slice
    case 11: return g_wbuf + OX;
    case 12: return g_wbuf + OCOVH;
    case 13: return g_wbuf + OSNW1;
    case 14: return g_wbuf + OSNW2;
    case 15: return g_wbuf + OWIH;
    case 16: return g_wbuf + OWHH;
    case 17: return g_wbuf + OACW1;       // 3072-row fused head weight
    case 20: return g_wbuf + OACW2;
    case 21: return g_wbuf + OCWW2;
    case 22: return g_wbuf + OCOVW1;
    case 23: return g_wbuf + OCOVW2;
    case 24: return g_wbuf + OCRW2;
    default: return nullptr;
  }
}

// ---------------- helpers ----------------
__device__ __forceinline__ float b2f(unsigned short u){
  unsigned int x = ((unsigned int)u) << 16;
  return __builtin_bit_cast(float, x);
}
__device__ __forceinline__ unsigned short f2b(float f){
  unsigned int u = __builtin_bit_cast(unsigned int, f);
  u += 0x7FFFu + ((u >> 16) & 1u);
  return (unsigned short)(u >> 16);
}
__device__ __forceinline__ float ldmix(const void* p, size_t i){
  return g_isf32 ? ((const float*)p)[i] : b2f(((const unsigned short*)p)[i]);
}
__device__ __forceinline__ float ldsel(bool f32, const void* p, size_t i){
  return f32 ? ((const float*)p)[i] : b2f(((const unsigned short*)p)[i]);
}
__device__ __forceinline__ float sigm(float x){ return 1.f/(1.f + __expf(-x)); }
__device__ __forceinline__ float tanh_f(float x){ float e = __expf(2.f*x); return 1.f - 2.f/(e + 1.f); }

__device__ __forceinline__ void gld16(const unsigned short* g, unsigned short* l){
  __builtin_amdgcn_global_load_lds(
      (__attribute__((address_space(1))) void*)(uintptr_t)g,
      (__attribute__((address_space(3))) void*)l,
      16, 0, 0);
}

// ---------------- dtype detect ----------------
__global__ __launch_bounds__(256) void detect_dtype(const unsigned short* x){
  __shared__ int cnt;
  if (threadIdx.x == 0) cnt = 0;
  __syncthreads();
  int c = 0;
  for (int i = threadIdx.x; i < 4096; i += 256){
    float f = b2f(x[2*i]);
    if (!(fabsf(f) < 1e10f)) c++;
  }
  atomicAdd(&cnt, c);
  __syncthreads();
  if (threadIdx.x == 0) g_isf32 = (cnt > 64) ? 1 : 0;
}

// ---------------- convert 14 arrays into g_wbuf (bf16) ----------------
__global__ __launch_bounds__(256) void cvt_all(
    const void* s0, const void* s1, const void* s2, const void* s3,
    const void* s4, const void* s5, const void* s6, const void* s7,
    const void* s8, const void* s9, const void* s10, const void* s11,
    const void* s12, const void* s13)
{
  const void* src; size_t off; int n;
  switch (blockIdx.y){
    case 0:  src=s0;  off=OX;     n=TOK*OBSD;  break;
    case 1:  src=s1;  off=OCOVH;  n=TOK*NACT;  break;
    case 2:  src=s2;  off=OSNW1;  n=HIDD*OBSD; break;
    case 3:  src=s3;  off=OSNW2;  n=HIDD*HIDD; break;
    case 4:  src=s4;  off=OWIH;   n=4*HIDD*HIDD; break;
    case 5:  src=s5;  off=OWHH;   n=4*HIDD*HIDD; break;
    case 6:  src=s6;  off=OACW1;  n=HIDD*HIDD; break;
    case 7:  src=s7;  off=OCWW1;  n=HIDD*HIDD; break;
    case 8:  src=s8;  off=OCRW1;  n=HIDD*HIDD; break;
    case 9:  src=s9;  off=OACW2;  n=NACT*HIDD; break;
    case 10: src=s10; off=OCWW2;  n=NACT*HIDD; break;
    case 11: src=s11; off=OCOVW1; n=HIDD*NACT; break;
    case 12: src=s12; off=OCOVW2; n=NACT*HIDD; break;
    default: src=s13; off=OCRW2;  n=HIDD;      break;
  }
  const bool f32 = (g_isf32 != 0);
  unsigned short* dst = g_wbuf + off;
  const int stride = gridDim.x * 256;
  for (int i = blockIdx.x*256 + threadIdx.x; i < n; i += stride){
    float v = f32 ? ((const float*)src)[i] : b2f(((const unsigned short*)src)[i]);
    dst[i] = f2b(v);
  }
}

// ---------------- tiled MFMA GEMM: C = act(A @ W^T + bias) ----------------
// ablk: A is blocked [cb][row][16] (g_hid2). bmode: 3-way bias select by col/1024.
__global__ __launch_bounds__(256) void gemm_bt(
    int a_id, int lda, int ablk, int w_id, int K,
    const void* __restrict__ b1, const void* __restrict__ b2, const void* __restrict__ b3,
    int bmode, int c_id, int ldc, int act, int cmode)
{
  __shared__ unsigned short sA[128*32];
  __shared__ unsigned short sB[128*32];
  const unsigned short* A = dev_buf(a_id);
  const unsigned short* W = dev_buf(w_id);
  void* C = dev_buf(c_id);

  const int tid  = threadIdx.x;
  const int wv   = tid >> 6, ln = tid & 63;
  const int quad = ln >> 4, l16 = ln & 15;
  const long bm = (long)blockIdx.y * 128, bn = (long)blockIdx.x * 128;
  const int wr = (wv >> 1) * 64, wc = (wv & 1) * 64;

  const f32x4 zf = {0.f, 0.f, 0.f, 0.f};
  f32x4 acc[4][4];
#pragma unroll
  for (int i = 0; i < 4; i++)
#pragma unroll
    for (int j = 0; j < 4; j++) acc[i][j] = zf;

  const int srow = wv*32 + (ln >> 2);
  const int scol = (ln & 3) * 8;
  const unsigned short* gA = A + (bm + srow)*(long)lda + scol;
  const unsigned short* gB = W + (bn + srow)*(long)K   + scol;
  unsigned short* lA = &sA[(wv*32)*32];
  unsigned short* lB = &sB[(wv*32)*32];

  for (int k0 = 0; k0 < K; k0 += 32){
    __syncthreads();
    if (ablk){
      const int kk = k0 + scol;
      const long cbase = (long)(kk >> 4) * ((long)TOK*16) + (kk & 15);
      gld16(A + cbase + (bm + srow)*16,      lA);
      gld16(A + cbase + (bm + srow + 16)*16, lA + 16*32);
    } else {
      gld16(gA + k0,                lA);
      gld16(gA + k0 + 16*(long)lda, lA + 16*32);
    }
    gld16(gB + k0,               lB);
    gld16(gB + k0 + 16*(long)K,  lB + 16*32);
    __syncthreads();
    bf16x8 af[4], bfr[4];
#pragma unroll
    for (int i = 0; i < 4; i++) af[i]  = *(const bf16x8*)&sA[(wr + 16*i + l16)*32 + quad*8];
#pragma unroll
    for (int j = 0; j < 4; j++) bfr[j] = *(const bf16x8*)&sB[(wc + 16*j + l16)*32 + quad*8];
#pragma unroll
    for (int i = 0; i < 4; i++)
#pragma unroll
      for (int j = 0; j < 4; j++)
        acc[i][j] = __builtin_amdgcn_mfma_f32_16x16x32_bf16(af[i], bfr[j], acc[i][j], 0, 0, 0);
  }

#pragma unroll
  for (int j = 0; j < 4; j++){
    const long col = bn + wc + 16*j + l16;
    float bb;
    if (bmode){
      const void* bp = (col < 1024) ? b1 : (col < 2048) ? b2 : b3;
      bb = ldmix(bp, col & 1023);
    } else {
      bb = (b1 ? ldmix(b1, col) : 0.f) + (b2 ? ldmix(b2, col) : 0.f);
    }
#pragma unroll
    for (int i = 0; i < 4; i++){
#pragma unroll
      for (int r = 0; r < 4; r++){
        const long row = bm + wr + 16*i + quad*4 + r;   // C/D: col=lane&15, row=quad*4+reg
        float v = acc[i][j][r] + bb;
        if (act) v = tanh_f(v);
        if (cmode) ((float*)C)[row*(long)ldc + col] = v;
        else ((unsigned short*)C)[row*(long)ldc + col] = f2b(v);
      }
    }
  }
}

// ---------------- two-level grid barrier (64 WGs = 8 groups x 8) ----------------
__device__ __forceinline__ void grid_barrier(){
  __syncthreads();
  if (threadIdx.x == 0){
    unsigned gen = __hip_atomic_load(&g_gen, __ATOMIC_RELAXED, __HIP_MEMORY_SCOPE_AGENT);
    const unsigned grp = blockIdx.x >> 3;
    unsigned a = __hip_atomic_fetch_add(&g_grp[grp], 1u, __ATOMIC_ACQ_REL, __HIP_MEMORY_SCOPE_AGENT);
    if (a == 7u){
      __hip_atomic_store(&g_grp[grp], 0u, __ATOMIC_RELAXED, __HIP_MEMORY_SCOPE_AGENT);
      unsigned b = __hip_atomic_fetch_add(&g_root, 1u, __ATOMIC_ACQ_REL, __HIP_MEMORY_SCOPE_AGENT);
      if (b == 7u){
        __hip_atomic_store(&g_root, 0u, __ATOMIC_RELAXED, __HIP_MEMORY_SCOPE_AGENT);
        __hip_atomic_fetch_add(&g_gen, 1u, __ATOMIC_ACQ_REL, __HIP_MEMORY_SCOPE_AGENT);
      } else {
        while (__hip_atomic_load(&g_gen, __ATOMIC_ACQUIRE, __HIP_MEMORY_SCOPE_AGENT) == gen)
          __builtin_amdgcn_s_sleep(1);
      }
    } else {
      while (__hip_atomic_load(&g_gen, __ATOMIC_ACQUIRE, __HIP_MEMORY_SCOPE_AGENT) == gen)
        __builtin_amdgcn_s_sleep(1);
    }
  }
  __syncthreads();
}

// ---------------- persistent LSTM scan (K-split, register-direct) ----------------
// 64 WGs; WG cb owns h cols [16cb,16cb+16). Wave wv owns K-quarter [256wv,256wv+256)
// and computes partial preacts for ALL 4 gates (w_hh quarter in 128 VGPRs).
// A-fragments load straight from global (coalesced) - no LDS staging.
// Cross-wave reduction via LDS slabs. One 2-level grid barrier per step.
__global__ __launch_bounds__(256, 1) void lstm_scan(
    const void* __restrict__ done_p,
    const void* __restrict__ h0_p,
    const void* __restrict__ c0_p)
{
  __shared__ float sP[16*64*20];   // [wave][gate][row][pad20] = 80 KB

  const int tid  = threadIdx.x;
  const int wv   = tid >> 6, ln = tid & 63;
  const int quad = ln >> 4, l16 = ln & 15;
  const int cb   = blockIdx.x;
  const int col0 = cb * 16;
  const int grow = tid >> 2;           // gate-phase row
  const int gcol = (tid & 3) * 4;
  const bool isf32 = (g_isf32 != 0);   // hoisted: one global read per kernel

  // cell state in registers
  float cst[4];
#pragma unroll
  for (int j = 0; j < 4; j++) cst[j] = ldsel(isf32, c0_p, grow*HIDD + col0 + gcol + j);

  // h0 -> blocked ping buffer (own block), masked by done[0]
  for (int e = tid; e < 1024; e += 256){
    int row = e >> 4, col = e & 15;
    float d0 = ldsel(isf32, done_p, row);
    float h0 = (d0 != 0.f) ? 0.f : ldsel(isf32, h0_p, row*HIDD + col0 + col);
    g_hp2[cb*1024 + e] = f2b(h0);
  }

  // preload w_hh K-quarter for all 4 gates: wreg[g][i], k = wv*256 + i*32 + quad*8
  const unsigned short* wbase = g_wbuf + OWHH;
  bf16x8 wreg[4][8];
#pragma unroll
  for (int g = 0; g < 4; g++)
#pragma unroll
    for (int i = 0; i < 8; i++)
      wreg[g][i] = *(const bf16x8*)&wbase[(size_t)(g*HIDD + col0 + l16)*HIDD + wv*256 + i*32 + quad*8];

  float dcur = ldsel(isf32, done_p, grow);   // done[0]
  grid_barrier();

  const f32x4 zf = {0.f, 0.f, 0.f, 0.f};

  for (int s = 0; s < TSTEPS; s++){
    const unsigned short* hb = g_hp2 + (s & 1)*65536;
    unsigned short*       hn = g_hp2 + ((s + 1) & 1)*65536;

    // prefetch step inputs (independent of h; overlap the MFMA phase)
    const int token = s*BATCH + grow;
    const float* xr = &g_xgf[(size_t)token*4096 + col0 + gcol];
    float4 xg0 = *(const float4*)(xr);
    float4 xg1 = *(const float4*)(xr + 1024);
    float4 xg2 = *(const float4*)(xr + 2048);
    float4 xg3 = *(const float4*)(xr + 3072);
    float dnext = (s < TSTEPS-1) ? ldsel(isf32, done_p, (s+1)*BATCH + grow) : 0.f;

    // MFMA phase: A direct from global (this wave's K-quarter), coalesced b128 loads
    const unsigned short* hq = hb + (size_t)(wv*16 + (quad >> 1))*1024 + l16*16 + (quad & 1)*8;
    f32x4 acc[4][4];   // [gate][row-tile]
#pragma unroll
    for (int g = 0; g < 4; g++)
#pragma unroll
      for (int rt = 0; rt < 4; rt++) acc[g][rt] = zf;
#pragma unroll
    for (int i = 0; i < 8; i++){
      bf16x8 af[4];
#pragma unroll
      for (int rt = 0; rt < 4; rt++)
        af[rt] = *(const bf16x8*)(hq + i*2048 + rt*256);
#pragma unroll
      for (int rt = 0; rt < 4; rt++)
#pragma unroll
        for (int g = 0; g < 4; g++)
          acc[g][rt] = __builtin_amdgcn_mfma_f32_16x16x32_bf16(af[rt], wreg[g][i], acc[g][rt], 0, 0, 0);
    }
    // write partial slabs
#pragma unroll
    for (int g = 0; g < 4; g++)
#pragma unroll
      for (int rt = 0; rt < 4; rt++)
#pragma unroll
        for (int r = 0; r < 4; r++)
          sP[((wv*4 + g)*64 + 16*rt + quad*4 + r)*20 + l16] = acc[g][rt][r];
    __syncthreads();

    // gate phase: sum 4 K-partials per gate, then LSTM cell update
    float4 pg[4];
#pragma unroll
    for (int g = 0; g < 4; g++){
      float4 p = {0.f, 0.f, 0.f, 0.f};
#pragma unroll
      for (int w2 = 0; w2 < 4; w2++){
        float4 t = *(const float4*)&sP[((w2*4 + g)*64 + grow)*20 + gcol];
        p.x += t.x; p.y += t.y; p.z += t.z; p.w += t.w;
      }
      pg[g] = p;
    }
    const bool last = (s == TSTEPS-1);
    unsigned short hs[4];
#pragma unroll
    for (int j = 0; j < 4; j++){
      float iv = sigm (((const float*)&pg[0])[j] + ((const float*)&xg0)[j]);
      float fv = sigm (((const float*)&pg[1])[j] + ((const float*)&xg1)[j]);
      float gv = tanh_f(((const float*)&pg[2])[j] + ((const float*)&xg2)[j]);
      float ov = sigm (((const float*)&pg[3])[j] + ((const float*)&xg3)[j]);
      float cp = (dcur != 0.f) ? 0.f : cst[j];
      float c  = fv*cp + iv*gv;
      float h  = ov * tanh_f(c);
      cst[j] = c;
      hs[j] = f2b(h);
      if (last){
        g_ht[grow*HIDD + col0 + gcol + j] = h;
        g_ct[grow*HIDD + col0 + gcol + j] = c;
      }
    }
    // blocked hidden store (2KB contiguous per WG)
    *(ushort4*)&g_hid2[(size_t)cb*((size_t)TOK*16) + (size_t)token*16 + gcol] = *(const ushort4*)hs;
    // next-h: pre-masked by done[s+1], write-through (agent scope) so fence walk stays small
    if (dnext != 0.f){ hs[0]=0; hs[1]=0; hs[2]=0; hs[3]=0; }
    unsigned v0 = (unsigned)hs[0] | ((unsigned)hs[1] << 16);
    unsigned v1 = (unsigned)hs[2] | ((unsigned)hs[3] << 16);
    unsigned* hnp = (unsigned*)&hn[cb*1024 + tid*4];
    __hip_atomic_store(hnp,     v0, __ATOMIC_RELAXED, __HIP_MEMORY_SCOPE_AGENT);
    __hip_atomic_store(hnp + 1, v1, __ATOMIC_RELAXED, __HIP_MEMORY_SCOPE_AGENT);
    dcur = dnext;   // rolling done register

    grid_barrier();
  }
}

// ---------------- value head: wave-per-row dot over cr slice of t3 ----------------
__global__ __launch_bounds__(256) void rowdot_kernel(const void* __restrict__ b)
{
  const unsigned short* A = g_t3 + 2048;     // cr cols of [TOK][3072]
  const unsigned short* w = g_wbuf + OCRW2;
  int row = blockIdx.x*4 + (threadIdx.x >> 6);
  int ln  = threadIdx.x & 63;
  float s = 0.f;
  for (int k = ln*8; k < HIDD; k += 512){
    bf16x8 av = *(const bf16x8*)&A[(size_t)row*3072 + k];
    bf16x8 wv = *(const bf16x8*)&w[k];
#pragma unroll
    for (int j = 0; j < 8; j++) s += b2f((unsigned short)av[j]) * b2f((unsigned short)wv[j]);
  }
  for (int o = 32; o; o >>= 1) s += __shfl_xor(s, o, 64);
  if (ln == 0) g_val[row] = s + ldmix(b, 0);
}

// ---------------- FINALIZE: only writer of d_out (fp32), full coverage ----------------
__global__ __launch_bounds__(256) void finalize(
    const int* __restrict__ action, float* __restrict__ dout)
{
  int row = blockIdx.x*4 + (threadIdx.x >> 6);
  int ln  = threadIdx.x & 63;
  size_t base = (size_t)row * NACT;
  float l0 = b2f(g_aco[base+ln])    + b2f(g_cwo[base+ln])   *b2f(g_covo[base+ln]);
  float l1 = b2f(g_aco[base+64+ln]) + b2f(g_cwo[base+64+ln])*b2f(g_covo[base+64+ln]);
  float mx = fmaxf(l0, l1);
  for (int o = 32; o; o >>= 1) mx = fmaxf(mx, __shfl_xor(mx, o, 64));
  float e0 = __expf(l0 - mx), e1 = __expf(l1 - mx);
  float sm = e0 + e1;
  for (int o = 32; o; o >>= 1) sm += __shfl_xor(sm, o, 64);
  float inv = 1.f/sm, ls = __logf(sm);
  float p0 = e0*inv, p1 = e1*inv;
  float lp0 = l0 - mx - ls, lp1 = l1 - mx - ls;
  dout[O_PROBS + base + ln]      = p0;
  dout[O_PROBS + base + 64 + ln] = p1;
  float ent = -(p0*lp0 + p1*lp1);
  for (int o = 32; o; o >>= 1) ent += __shfl_xor(ent, o, 64);
  int a = action[row];
  float lpa = (a == ln) ? lp0 : (a == ln + 64) ? lp1 : 0.f;
  for (int o = 32; o; o >>= 1) lpa += __shfl_xor(lpa, o, 64);
  if (ln == 0){
    dout[O_LOGPA + row] = lpa;
    dout[O_ENT   + row] = ent;
  }
  int gtid = blockIdx.x*256 + threadIdx.x;
  if (gtid < TOK)        dout[O_VAL + gtid] = g_val[gtid];
  if (gtid < BATCH*HIDD){
    dout[O_HT + gtid] = g_ht[gtid];
    dout[O_CT + gtid] = g_ct[gtid];
  }
}

// ---------------- host ----------------
extern "C" void kernel_launch(void* const* d_in, const int* in_sizes, int n_in,
                              void* d_out, int out_size, void* d_ws, size_t ws_size,
                              hipStream_t stream)
{
  (void)in_sizes; (void)n_in; (void)out_size; (void)d_ws; (void)ws_size;
  float* dout = (float*)d_out;

  hipLaunchKernelGGL(detect_dtype, dim3(1), dim3(256), 0, stream,
                     (const unsigned short*)d_in[0]);

  hipLaunchKernelGGL(cvt_all, dim3(512, 14), dim3(256), 0, stream,
                     d_in[0], d_in[2], d_in[6], d_in[8], d_in[10], d_in[11],
                     d_in[18], d_in[26], d_in[14], d_in[20], d_in[28],
                     d_in[22], d_in[24], d_in[16]);

  auto gemm = [&](int a_id, int lda, int ablk, int w_id, int K,
                  const void* b1, const void* b2, const void* b3, int bmode,
                  int c_id, int ldc, int N, int act, int cmode){
    hipLaunchKernelGGL(gemm_bt, dim3(N/128, TOK/128), dim3(256), 0, stream,
                       a_id, lda, ablk, w_id, K, b1, b2, b3, bmode,
                       c_id, ldc, act, cmode);
  };

  // perception MLP + hoisted input-gate GEMM
  gemm(11, OBSD, 0, 13, OBSD, d_in[7],  nullptr, nullptr, 0, 1, HIDD,   HIDD,   1, 0);
  gemm(1,  HIDD, 0, 14, HIDD, d_in[9],  nullptr, nullptr, 0, 2, HIDD,   HIDD,   1, 0);
  gemm(2,  HIDD, 0, 15, HIDD, d_in[12], d_in[13], nullptr, 0, 8, 4*HIDD, 4*HIDD, 0, 1);

  // sequential LSTM scan (persistent, 64 WGs, 1 grid barrier/step)
  hipLaunchKernelGGL(lstm_scan, dim3(64), dim3(256), 0, stream,
                     d_in[1], d_in[3], d_in[4]);

  // fused head hidden GEMM: t3 = tanh(hidden @ [ac|cw|cr]w1^T + b), N=3072, blocked A
  gemm(3, 3072, 1, 17, HIDD, d_in[19], d_in[27], d_in[15], 1, 4, 3*HIDD, 3*HIDD, 1, 0);
  // output heads
  gemm(4,  3072, 0, 20, HIDD, d_in[21], nullptr, nullptr, 0, 5, NACT, NACT, 0, 0);
  gemm(9,  3072, 0, 21, HIDD, d_in[29], nullptr, nullptr, 0, 6, NACT, NACT, 0, 0);
  gemm(12, NACT, 0, 22, NACT, d_in[23], nullptr, nullptr, 0, 1, HIDD, HIDD, 1, 0);
  gemm(1,  HIDD, 0, 23, HIDD, d_in[25], nullptr, nullptr, 0, 7, NACT, NACT, 0, 0);

  // value head (staged)
  hipLaunchKernelGGL(rowdot_kernel, dim3(TOK/4), dim3(256), 0, stream, d_in[17]);

  // single final writer of d_out
  hipLaunchKernelGGL(finalize, dim3(TOK/4), dim3(256), 0, stream,
                     (const int*)d_in[5], dout);
}